// Round 1
// baseline (328.788 us; speedup 1.0000x reference)
//
#include <hip/hip_runtime.h>

#define B_      32
#define HW_     3136
#define C_      512
#define H_      128
#define NCHUNK  32
#define ROWS_PER_CHUNK (HW_ / NCHUNK)   // 98

// ---------------------------------------------------------------------------
// Kernel 1: per-(batch, chunk) column sums of (c + w + h).
// Grid: B_*NCHUNK blocks, 256 threads. Each thread owns one float2 column
// (256 * 2 = 512 = C_) and loops over 98 rows. Deterministic (no atomics).
// ---------------------------------------------------------------------------
__global__ __launch_bounds__(256) void ps_kernel(
    const float* __restrict__ c_e,
    const float* __restrict__ w_e,
    const float* __restrict__ h_e,
    float* __restrict__ partial)
{
    const int blk = blockIdx.x;            // b*NCHUNK + k
    const int b   = blk / NCHUNK;
    const int k   = blk - b * NCHUNK;
    const int t   = threadIdx.x;           // 0..255 -> float2 column

    const long row0 = (long)b * HW_ + (long)k * ROWS_PER_CHUNK;
    const float2* __restrict__ c2 = (const float2*)c_e;
    const float2* __restrict__ w2 = (const float2*)w_e;
    const float2* __restrict__ h2 = (const float2*)h_e;

    long base = row0 * (C_ / 2) + t;
    float ax = 0.f, ay = 0.f;
    #pragma unroll 2
    for (int r = 0; r < ROWS_PER_CHUNK; ++r) {
        float2 a = c2[base];
        float2 v = w2[base];
        float2 u = h2[base];
        ax += a.x + v.x + u.x;
        ay += a.y + v.y + u.y;
        base += (C_ / 2);
    }
    float2 o; o.x = ax; o.y = ay;
    ((float2*)partial)[(long)blk * (C_ / 2) + t] = o;
}

// ---------------------------------------------------------------------------
// Kernel 2: reduce partials -> mean s (B,C); fc1 + tanh-GELU; fc2 + bias;
// 3-way softmax -> wbuf (B, 3*C). One block per batch, 256 threads.
// ---------------------------------------------------------------------------
__global__ __launch_bounds__(256) void mlp_kernel(
    const float* __restrict__ partial,
    const float* __restrict__ fc1_w,
    const float* __restrict__ fc1_b,
    const float* __restrict__ fc2_w,
    const float* __restrict__ fc2_b,
    float* __restrict__ wbuf)
{
    __shared__ float s_lds[C_];
    __shared__ float y_lds[H_];

    const int b = blockIdx.x;
    const int t = threadIdx.x;

    // mean over HW (sum of NCHUNK partials)
    for (int c = t; c < C_; c += 256) {
        float acc = 0.f;
        #pragma unroll
        for (int k = 0; k < NCHUNK; ++k)
            acc += partial[(long)(b * NCHUNK + k) * C_ + c];
        s_lds[c] = acc * (1.0f / (float)HW_);
    }
    __syncthreads();

    // fc1 + GELU(tanh approx)
    if (t < H_) {
        float acc = fc1_b[t];
        const float* __restrict__ wr = fc1_w + (long)t * C_;
        #pragma unroll 8
        for (int c = 0; c < C_; ++c) acc += s_lds[c] * wr[c];
        const float x  = acc;
        const float u  = 0.7978845608028654f * (x + 0.044715f * x * x * x);
        y_lds[t] = 0.5f * x * (1.0f + tanhf(u));
    }
    __syncthreads();

    // fc2 + softmax over the 3 branches
    for (int c = t; c < C_; c += 256) {
        float lg[3];
        #pragma unroll
        for (int j = 0; j < 3; ++j) {
            const int row = j * C_ + c;
            float acc = fc2_b[row];
            const float* __restrict__ wr = fc2_w + (long)row * H_;
            #pragma unroll 8
            for (int h = 0; h < H_; ++h) acc += y_lds[h] * wr[h];
            lg[j] = acc;
        }
        const float m  = fmaxf(lg[0], fmaxf(lg[1], lg[2]));
        const float e0 = __expf(lg[0] - m);
        const float e1 = __expf(lg[1] - m);
        const float e2 = __expf(lg[2] - m);
        const float inv = 1.0f / (e0 + e1 + e2);
        float* __restrict__ wb = wbuf + (long)b * 3 * C_;
        wb[0 * C_ + c] = e0 * inv;
        wb[1 * C_ + c] = e1 * inv;
        wb[2 * C_ + c] = e2 * inv;
    }
}

// ---------------------------------------------------------------------------
// Kernel 3: out = c*w0 + w*w1 + h*w2 (broadcast per batch). float4 grid-stride.
// ---------------------------------------------------------------------------
__global__ __launch_bounds__(256) void out_kernel(
    const float* __restrict__ c_e,
    const float* __restrict__ w_e,
    const float* __restrict__ h_e,
    const float* __restrict__ wbuf,
    float* __restrict__ out)
{
    const float4* __restrict__ c4 = (const float4*)c_e;
    const float4* __restrict__ w4 = (const float4*)w_e;
    const float4* __restrict__ h4 = (const float4*)h_e;
    float4* __restrict__ o4       = (float4*)out;
    const float4* __restrict__ wb4 = (const float4*)wbuf;

    const int total = B_ * HW_ * (C_ / 4);     // 12,845,056 < 2^31
    const int stride = gridDim.x * blockDim.x;
    for (int idx = blockIdx.x * blockDim.x + threadIdx.x; idx < total; idx += stride) {
        const int row  = idx >> 7;             // C_/4 = 128
        const int col4 = idx & 127;
        const int b    = row / HW_;
        const float4* __restrict__ wb = wb4 + (long)b * (3 * C_ / 4);
        const float4 w0 = wb[col4];
        const float4 w1 = wb[128 + col4];
        const float4 w2 = wb[256 + col4];
        const float4 a = c4[idx];
        const float4 v = w4[idx];
        const float4 u = h4[idx];
        float4 o;
        o.x = a.x * w0.x + v.x * w1.x + u.x * w2.x;
        o.y = a.y * w0.y + v.y * w1.y + u.y * w2.y;
        o.z = a.z * w0.z + v.z * w1.z + u.z * w2.z;
        o.w = a.w * w0.w + v.w * w1.w + u.w * w2.w;
        o4[idx] = o;
    }
}

// ---------------------------------------------------------------------------
extern "C" void kernel_launch(void* const* d_in, const int* in_sizes, int n_in,
                              void* d_out, int out_size, void* d_ws, size_t ws_size,
                              hipStream_t stream)
{
    const float* c_e   = (const float*)d_in[0];
    const float* w_e   = (const float*)d_in[1];
    const float* h_e   = (const float*)d_in[2];
    const float* fc1_w = (const float*)d_in[3];
    const float* fc1_b = (const float*)d_in[4];
    const float* fc2_w = (const float*)d_in[5];
    const float* fc2_b = (const float*)d_in[6];
    float* out = (float*)d_out;

    // workspace layout (floats): [partial: B*NCHUNK*C][wbuf: B*3*C]
    float* partial = (float*)d_ws;                       // 2 MB
    float* wbuf    = partial + (long)B_ * NCHUNK * C_;   // 192 KB

    ps_kernel<<<B_ * NCHUNK, 256, 0, stream>>>(c_e, w_e, h_e, partial);
    mlp_kernel<<<B_, 256, 0, stream>>>(partial, fc1_w, fc1_b, fc2_w, fc2_b, wbuf);
    out_kernel<<<2048, 256, 0, stream>>>(c_e, w_e, h_e, wbuf, out);
}